// Round 6
// baseline (137762.585 us; speedup 1.0000x reference)
//
#include <hip/hip_runtime.h>
#include <math.h>

#define T 16384

typedef float f32x4  __attribute__((ext_vector_type(4)));
typedef float f32x16 __attribute__((ext_vector_type(16)));

__device__ __forceinline__ float softplusf_(float x) {
    return (x > 15.f) ? x : __logf(1.f + __expf(x));
}
__device__ __forceinline__ float sigmoidf_(float x) {
    return 1.f / (1.f + __expf(-x));
}
__device__ __forceinline__ float tanh_fast(float x) {
    float xc = fminf(fmaxf(x, -15.f), 15.f);
    float e = __expf(2.f * xc);
    return (e - 1.f) / (e + 1.f);
}

// ---------------------------------------------------------------------------
// Precompute x-dependent matvec parts + logit(eps_u) (fully parallel).
// ---------------------------------------------------------------------------
__global__ __launch_bounds__(256) void k_pre(
    const float* __restrict__ x, const float* __restrict__ eu_g,
    const float* __restrict__ Wqy, const float* __restrict__ Wenc,
    const float* __restrict__ Wih,
    float* __restrict__ Aq, float* __restrict__ Ae, float* __restrict__ Ah,
    float* __restrict__ leu_g)
{
    __shared__ float xs[16 * 128];
    const int t0 = blockIdx.x * 16;
    for (int r = threadIdx.x; r < 16 * 128; r += 256) xs[r] = x[t0 * 128 + r];
    __syncthreads();
    const int j = threadIdx.x;
    if (j < 16) {
        float eu = eu_g[t0 + j];
        leu_g[t0 + j] = __logf(eu) - __logf(1.f - eu);
    }
    for (int tt = 0; tt < 16; ++tt) {
        float aq = 0.f, ae = 0.f;
#pragma unroll 8
        for (int i = 0; i < 128; ++i) {
            float xv = xs[tt * 128 + i];
            aq = fmaf(xv, Wqy[i * 256 + j], aq);
            ae = fmaf(xv, Wenc[i * 256 + j], ae);
        }
        Aq[(size_t)(t0 + tt) * 256 + j] = aq;
        Ae[(size_t)(t0 + tt) * 256 + j] = ae;
    }
    if (j < 128) {
        for (int tt = 0; tt < 16; ++tt) {
            float ah = 0.f;
#pragma unroll 8
            for (int i = 0; i < 128; ++i)
                ah = fmaf(xs[tt * 128 + i], Wih[(65 + i) * 128 + j], ah);
            Ah[(size_t)(t0 + tt) * 128 + j] = ah;
        }
    }
}

// ---------------------------------------------------------------------------
// Sequential scan. 1 block, 256 threads (4 waves = 1/SIMD) so each wave can
// have up to 512 VGPRs: ~355 weight floats/thread stay register-resident.
// W_q_y h-part (128 KB) lives in LDS. All per-step LDS reads are <=2-way.
// Summation orders are bit-identical to the round-3/4/5 passing kernel.
// ---------------------------------------------------------------------------
__global__
__attribute__((amdgpu_flat_work_group_size(256, 256)))
__attribute__((amdgpu_waves_per_eu(1, 1)))
void k_scan(
    const float* __restrict__ Wqy, const float* __restrict__ qpr,
    const float* __restrict__ Wenc,
    const float* __restrict__ Wem0, const float* __restrict__ Wes0,
    const float* __restrict__ Wih, const float* __restrict__ Whh,
    const float* __restrict__ yin_g, const float* __restrict__ leu_g,
    const float* __restrict__ ez_g,
    const float* __restrict__ Aq, const float* __restrict__ Ae,
    const float* __restrict__ Ah,
    float* __restrict__ h_st, float* __restrict__ z_st,
    float* __restrict__ em_st, float* __restrict__ es_st,
    float* __restrict__ y_st)
{
    const int tid = threadIdx.x;
    const int j   = tid;                       // S1/S3: one output per thread
    const int m4  = tid >> 2, k4 = (tid >> 1) & 1, c4n = tid & 1;   // S4
    const int o5  = tid >> 1, c5n = tid & 1;                        // S5
    const int cA4 = 2 * c4n, cB4 = 2 * c4n + 1;    // S4 original chunk ids
    const int XA  = 2 * c5n, XB = 2 * c5n + 1;     // S5 original chunk ids

    // rotated-storage positions (write side) for ehR / hR
    const int cR = j >> 6;
    const int pR = cR * 64 + (((j & 63) - 8 * cR) & 63);
    const int oX = o5 >> 5;
    const int pH = oX * 32 + (((o5 & 31) - 8 * oX) & 31);

    // ---- LDS (~147.5 KB) ----
    __shared__ __align__(16) f32x4 wq4[32][256];     // 128 KB: W_q_y h-part
    __shared__ __align__(16) float s_aq[4][256];
    __shared__ __align__(16) float s_ae[4][256];
    __shared__ __align__(16) float s_ah[4][128];
    __shared__ __align__(16) float s_ez[4][64];
    __shared__ __align__(16) float s_yin[4];
    __shared__ __align__(16) float s_leu[4];
    __shared__ __align__(16) float t_h[4][128];
    __shared__ __align__(16) float t_z[4][64];
    __shared__ __align__(16) float t_em[4][64];
    __shared__ __align__(16) float t_es[4][64];
    __shared__ float t_y[4];
    __shared__ __align__(16) float h_lds[2][128];
    __shared__ __align__(16) float hR[2][128];       // rot-stored h for S5
    __shared__ __align__(16) float eh_lds[256];
    __shared__ __align__(16) float ehR[256];         // rot-stored eh for S4
    __shared__ __align__(16) float z_lds[64];
    __shared__ float red2[4];

    // ---- persistent weights in registers (all indices constant after unroll)
    f32x16 weh[8];        // S3: W_enc h-rows 129..256, col j
#pragma unroll
    for (int v = 0; v < 8; ++v)
#pragma unroll
        for (int e = 0; e < 16; ++e)
            weh[v][e] = Wenc[(129 + 16 * v + e) * 256 + j];
    const float wey = Wenc[128 * 256 + j];
    const float qpj = qpr[j];

    f32x16 wms[8];        // S4: 2 sub-chunks x 64, pre-rotated (rot = 8*chunk)
    {
        const float* Wm = k4 ? Wes0 : Wem0;
#pragma unroll
        for (int v = 0; v < 4; ++v)
#pragma unroll
            for (int e = 0; e < 16; ++e) {
                int kk = 16 * v + e;
                wms[v][e]     = Wm[(cA4 * 64 + ((kk + 8 * cA4) & 63)) * 64 + m4];
                wms[4 + v][e] = Wm[(cB4 * 64 + ((kk + 8 * cB4) & 63)) * 64 + m4];
            }
    }
    f32x16 wzA, wzB, whA[2], whB[2];   // S5: z natural, h pre-rotated
#pragma unroll
    for (int e = 0; e < 16; ++e) {
        wzA[e] = Wih[(1 + XA * 16 + e) * 128 + o5];
        wzB[e] = Wih[(1 + XB * 16 + e) * 128 + o5];
    }
#pragma unroll
    for (int v = 0; v < 2; ++v)
#pragma unroll
        for (int e = 0; e < 16; ++e) {
            int k = 16 * v + e;
            whA[v][e] = Whh[(XA * 32 + ((k + 8 * XA) & 31)) * 128 + o5];
            whB[v][e] = Whh[(XB * 32 + ((k + 8 * XB) & 31)) * 128 + o5];
        }
    const float wihy = Wih[o5];

    // W_q_y h-part -> LDS [32][256] (col j per thread)
#pragma unroll 4
    for (int kq = 0; kq < 32; ++kq) {
        f32x4 v;
        v[0] = Wqy[(128 + 4 * kq + 0) * 256 + j];
        v[1] = Wqy[(128 + 4 * kq + 1) * 256 + j];
        v[2] = Wqy[(128 + 4 * kq + 2) * 256 + j];
        v[3] = Wqy[(128 + 4 * kq + 3) * 256 + j];
        wq4[kq][j] = v;
    }
    if (tid < 128) {
        h_lds[0][tid] = 0.f;
        hR[0][tid] = 0.f;
    }

    // ---- staging: global -> regs (early) -> LDS (late) ----
    f32x4 pA, pB, pC;
    auto load_regs = [&](int t0) {
        pA = ((const f32x4*)(Aq + (size_t)t0 * 256))[tid];
        pB = ((const f32x4*)(Ae + (size_t)t0 * 256))[tid];
        if (tid < 128)       pC = ((const f32x4*)(Ah + (size_t)t0 * 128))[tid];
        else if (tid < 192)  pC = ((const f32x4*)(ez_g + (size_t)t0 * 64))[tid - 128];
        else if (tid == 192) pC = *(const f32x4*)(yin_g + t0);
        else if (tid == 193) pC = *(const f32x4*)(leu_g + t0);
    };
    auto write_regs = [&]() {
        ((f32x4*)&s_aq[0][0])[tid] = pA;
        ((f32x4*)&s_ae[0][0])[tid] = pB;
        if (tid < 128)       ((f32x4*)&s_ah[0][0])[tid] = pC;
        else if (tid < 192)  ((f32x4*)&s_ez[0][0])[tid - 128] = pC;
        else if (tid == 192) *(f32x4*)s_yin = pC;
        else if (tid == 193) *(f32x4*)s_leu = pC;
    };
    auto flushb = [&](int t0) {
        if (tid < 64)
            ((f32x4*)(es_st + (size_t)t0 * 64))[tid] = ((const f32x4*)&t_es[0][0])[tid];
        if (tid < 128) {
            ((f32x4*)(h_st + (size_t)t0 * 128))[tid] = ((const f32x4*)&t_h[0][0])[tid];
        } else if (tid < 192) {
            ((f32x4*)(z_st + (size_t)t0 * 64))[tid - 128] = ((const f32x4*)&t_z[0][0])[tid - 128];
        } else {
            ((f32x4*)(em_st + (size_t)t0 * 64))[tid - 192] = ((const f32x4*)&t_em[0][0])[tid - 192];
        }
        if (tid >= 252) y_st[t0 + (tid - 252)] = t_y[tid - 252];
    };

    load_regs(0);
    write_regs();
    __syncthreads();

    for (int t0 = 0; t0 < T; t0 += 4) {
        const int tnb = (t0 + 4 < T) ? t0 + 4 : t0;
        load_regs(tnb);                                // issue early (T14)

        for (int tt = 0; tt < 4; ++tt) {
            const int t = t0 + tt;
            const int cur = t & 1, nxt = cur ^ 1;
            const float aq  = s_aq[tt][j];
            const float ae  = s_ae[tt][j];
            const float yin = s_yin[tt];
            const float leu = s_leu[tt];
            const float ez  = s_ez[tt][m4];
            const float ah  = s_ah[tt][o5];
            const f32x4* __restrict__ hb4 = (const f32x4*)&h_lds[cur][0];

            float y_t, ehdot;
            if (yin == -1.0f) {
                // fused S1(q-dot) + S3(eh-dot), shared h broadcast reads
                float a0 = 0.f, a1 = 0.f, a2 = 0.f, a3 = 0.f;   // q chunk0
                float A0 = 0.f, A1 = 0.f, A2 = 0.f, A3 = 0.f;   // q chunk1
                float e0 = 0.f, e1 = 0.f, e2 = 0.f, e3 = 0.f;   // e chunk0
                float E0 = 0.f, E1 = 0.f, E2 = 0.f, E3 = 0.f;   // e chunk1
#pragma unroll
                for (int kq = 0; kq < 16; ++kq) {
                    f32x4 h_ = hb4[kq];
                    f32x4 w_ = wq4[kq][j];
                    a0 = fmaf(h_[0], w_[0], a0); a1 = fmaf(h_[1], w_[1], a1);
                    a2 = fmaf(h_[2], w_[2], a2); a3 = fmaf(h_[3], w_[3], a3);
                    e0 = fmaf(h_[0], weh[kq >> 2][(kq & 3) * 4 + 0], e0);
                    e1 = fmaf(h_[1], weh[kq >> 2][(kq & 3) * 4 + 1], e1);
                    e2 = fmaf(h_[2], weh[kq >> 2][(kq & 3) * 4 + 2], e2);
                    e3 = fmaf(h_[3], weh[kq >> 2][(kq & 3) * 4 + 3], e3);
                }
#pragma unroll
                for (int kq = 16; kq < 32; ++kq) {
                    f32x4 h_ = hb4[kq];
                    f32x4 w_ = wq4[kq][j];
                    A0 = fmaf(h_[0], w_[0], A0); A1 = fmaf(h_[1], w_[1], A1);
                    A2 = fmaf(h_[2], w_[2], A2); A3 = fmaf(h_[3], w_[3], A3);
                    E0 = fmaf(h_[0], weh[kq >> 2][(kq & 3) * 4 + 0], E0);
                    E1 = fmaf(h_[1], weh[kq >> 2][(kq & 3) * 4 + 1], E1);
                    E2 = fmaf(h_[2], weh[kq >> 2][(kq & 3) * 4 + 2], E2);
                    E3 = fmaf(h_[3], weh[kq >> 2][(kq & 3) * 4 + 3], E3);
                }
                float sQ = ((a0 + a1) + (a2 + a3)) + ((A0 + A1) + (A2 + A3));
                ehdot    = ((e0 + e1) + (e2 + e3)) + ((E0 + E1) + (E2 + E3));
                float qh = fmaxf(aq + sQ, 0.f);
                float cq = qh * qpj;
#pragma unroll
                for (int d = 1; d < 64; d <<= 1) cq += __shfl_xor(cq, d);
                if ((tid & 63) == 0) red2[tid >> 6] = cq;
                __syncthreads();                           // B1
                float qlog = (red2[0] + red2[1]) + (red2[2] + red2[3]);
                y_t = sigmoidf_(leu + qlog);
            } else {
                float e0 = 0.f, e1 = 0.f, e2 = 0.f, e3 = 0.f;
                float E0 = 0.f, E1 = 0.f, E2 = 0.f, E3 = 0.f;
#pragma unroll
                for (int kq = 0; kq < 16; ++kq) {
                    f32x4 h_ = hb4[kq];
                    e0 = fmaf(h_[0], weh[kq >> 2][(kq & 3) * 4 + 0], e0);
                    e1 = fmaf(h_[1], weh[kq >> 2][(kq & 3) * 4 + 1], e1);
                    e2 = fmaf(h_[2], weh[kq >> 2][(kq & 3) * 4 + 2], e2);
                    e3 = fmaf(h_[3], weh[kq >> 2][(kq & 3) * 4 + 3], e3);
                }
#pragma unroll
                for (int kq = 16; kq < 32; ++kq) {
                    f32x4 h_ = hb4[kq];
                    E0 = fmaf(h_[0], weh[kq >> 2][(kq & 3) * 4 + 0], E0);
                    E1 = fmaf(h_[1], weh[kq >> 2][(kq & 3) * 4 + 1], E1);
                    E2 = fmaf(h_[2], weh[kq >> 2][(kq & 3) * 4 + 2], E2);
                    E3 = fmaf(h_[3], weh[kq >> 2][(kq & 3) * 4 + 3], E3);
                }
                ehdot = ((e0 + e1) + (e2 + e3)) + ((E0 + E1) + (E2 + E3));
                y_t = yin;
            }

            // S3 finalize: eh = relu(Ae + y*wey + h-dot); write linear + rotated
            {
                float eh = fmaxf(fmaf(y_t, wey, ae) + ehdot, 0.f);
                eh_lds[j] = eh;
                ehR[pR] = eh;
            }
            __syncthreads();                               // B3

            // S4: em/es over eh(256), 2 sub-chunks (rot-stored reads, linear)
            {
                const f32x4* __restrict__ eb4 = (const f32x4*)ehR;
                float b0 = 0.f, b1 = 0.f, b2 = 0.f, b3 = 0.f;
                float B0 = 0.f, B1v = 0.f, B2 = 0.f, B3 = 0.f;
#pragma unroll
                for (int kq = 0; kq < 16; ++kq) {
                    f32x4 eA = eb4[cA4 * 16 + kq];
                    b0 = fmaf(eA[0], wms[kq >> 2][(kq & 3) * 4 + 0], b0);
                    b1 = fmaf(eA[1], wms[kq >> 2][(kq & 3) * 4 + 1], b1);
                    b2 = fmaf(eA[2], wms[kq >> 2][(kq & 3) * 4 + 2], b2);
                    b3 = fmaf(eA[3], wms[kq >> 2][(kq & 3) * 4 + 3], b3);
                }
#pragma unroll
                for (int kq = 0; kq < 16; ++kq) {
                    f32x4 eB = eb4[cB4 * 16 + kq];
                    B0 = fmaf(eB[0], wms[4 + (kq >> 2)][(kq & 3) * 4 + 0], B0);
                    B1v = fmaf(eB[1], wms[4 + (kq >> 2)][(kq & 3) * 4 + 1], B1v);
                    B2 = fmaf(eB[2], wms[4 + (kq >> 2)][(kq & 3) * 4 + 2], B2);
                    B3 = fmaf(eB[3], wms[4 + (kq >> 2)][(kq & 3) * 4 + 3], B3);
                }
                float s = ((b0 + b1) + (b2 + b3)) + ((B0 + B1v) + (B2 + B3));
                s += __shfl_xor(s, 1);                     // combine c4n
                float other = __shfl_xor(s, 2);            // k4 partner
                float em_pre = k4 ? other : s;
                float es_pre = k4 ? s : other;
                float es = softplusf_(es_pre);
                float zm = fmaf(ez, es, em_pre);
                if ((tid & 3) == 0) {
                    z_lds[m4] = zm;
                    t_z[tt][m4] = zm; t_em[tt][m4] = em_pre; t_es[tt][m4] = es;
                }
            }
            __syncthreads();                               // B4

            // S5: h_new = tanh(Ah + y*wihy + z@Wih_z + h@W_hh), 2 sub-chunks
            {
                const f32x4* __restrict__ zb4 = (const f32x4*)z_lds;
                const f32x4* __restrict__ hR4 = (const f32x4*)&hR[cur][0];
                float g0 = 0.f, g1 = 0.f, g2 = 0.f, g3 = 0.f;
                float G0 = 0.f, G1 = 0.f, G2 = 0.f, G3 = 0.f;
#pragma unroll
                for (int kq = 0; kq < 4; ++kq) {           // z part, chunk A
                    f32x4 zv = zb4[XA * 4 + kq];
                    g0 = fmaf(zv[0], wzA[4 * kq + 0], g0);
                    g1 = fmaf(zv[1], wzA[4 * kq + 1], g1);
                    g2 = fmaf(zv[2], wzA[4 * kq + 2], g2);
                    g3 = fmaf(zv[3], wzA[4 * kq + 3], g3);
                }
#pragma unroll
                for (int kq = 0; kq < 8; ++kq) {           // h part, chunk A
                    f32x4 hv = hR4[XA * 8 + kq];
                    g0 = fmaf(hv[0], whA[kq >> 2][(kq & 3) * 4 + 0], g0);
                    g1 = fmaf(hv[1], whA[kq >> 2][(kq & 3) * 4 + 1], g1);
                    g2 = fmaf(hv[2], whA[kq >> 2][(kq & 3) * 4 + 2], g2);
                    g3 = fmaf(hv[3], whA[kq >> 2][(kq & 3) * 4 + 3], g3);
                }
#pragma unroll
                for (int kq = 0; kq < 4; ++kq) {           // z part, chunk B
                    f32x4 zv = zb4[XB * 4 + kq];
                    G0 = fmaf(zv[0], wzB[4 * kq + 0], G0);
                    G1 = fmaf(zv[1], wzB[4 * kq + 1], G1);
                    G2 = fmaf(zv[2], wzB[4 * kq + 2], G2);
                    G3 = fmaf(zv[3], wzB[4 * kq + 3], G3);
                }
#pragma unroll
                for (int kq = 0; kq < 8; ++kq) {           // h part, chunk B
                    f32x4 hv = hR4[XB * 8 + kq];
                    G0 = fmaf(hv[0], whB[kq >> 2][(kq & 3) * 4 + 0], G0);
                    G1 = fmaf(hv[1], whB[kq >> 2][(kq & 3) * 4 + 1], G1);
                    G2 = fmaf(hv[2], whB[kq >> 2][(kq & 3) * 4 + 2], G2);
                    G3 = fmaf(hv[3], whB[kq >> 2][(kq & 3) * 4 + 3], G3);
                }
                float s = ((g0 + g1) + (g2 + g3)) + ((G0 + G1) + (G2 + G3));
                s += __shfl_xor(s, 1);                     // combine c5n
                float hn = tanh_fast(fmaf(y_t, wihy, ah) + s);
                if (c5n == 0) {
                    h_lds[nxt][o5] = hn;
                    hR[nxt][pH] = hn;
                    t_h[tt][o5] = hn;
                }
                if (tid == 0) t_y[tt] = y_t;
            }
            __syncthreads();                               // B5
        }

        flushb(t0);
        write_regs();
        __syncthreads();                                   // batch barrier
    }
}

// ---------------------------------------------------------------------------
// Post-pass: one block per timestep (unchanged).
// ---------------------------------------------------------------------------
__global__ __launch_bounds__(256) void k_post(
    const float* __restrict__ x, const float* __restrict__ yin_g,
    const float* __restrict__ Wpz, const float* __restrict__ Wpzm,
    const float* __restrict__ Wpzs,
    const float* __restrict__ Wpy, const float* __restrict__ ppr,
    const float* __restrict__ Wqy, const float* __restrict__ qpr,
    const float* __restrict__ Wd, const float* __restrict__ Wdm,
    const float* __restrict__ Wds,
    const float* __restrict__ Aq,
    const float* __restrict__ h_st, const float* __restrict__ z_st,
    const float* __restrict__ em_st, const float* __restrict__ es_st,
    const float* __restrict__ y_st,
    float* __restrict__ part)
{
    const float CC = -0.9189385332046727f;  // -0.5*log(2*pi)
    const int t = blockIdx.x;
    const int tid = threadIdx.x;
    __shared__ float xp[128], xdv[128], xcv[128], hp[128];
    __shared__ float zp[64], ztv[64], emv[64], esv[64];
    __shared__ float pzh[256], dhv[256];
    __shared__ float pmv[64], psv[64], dmv[128], dsv[128];
    __shared__ float rl[16];

    const int tp = t ? (t - 1) : (T - 1);
    if (tid < 128) {
        xp[tid]  = x[(size_t)tp * 128 + tid];
        xdv[tid] = t ? x[(size_t)(t - 1) * 128 + tid] : 0.f;
        xcv[tid] = x[(size_t)t * 128 + tid];
        hp[tid]  = t ? h_st[(size_t)(t - 1) * 128 + tid] : 0.f;
    } else {
        int m = tid - 128;
        if (m < 64) {
            zp[m]  = t ? z_st[(size_t)(t - 1) * 64 + m] : 0.f;
            ztv[m] = z_st[(size_t)t * 64 + m];
        } else {
            m -= 64;
            emv[m] = em_st[(size_t)t * 64 + m];
            esv[m] = es_st[(size_t)t * 64 + m];
        }
    }
    __syncthreads();

    const float y_t = y_st[t];
    const float y_prev = t ? y_st[t - 1] : 0.f;
    const float lf = (yin_g[t] != -1.0f) ? 1.f : 0.f;
    const int jj = tid;

    float ap = 0.f;
#pragma unroll 4
    for (int i = 0; i < 128; ++i) ap = fmaf(xp[i], Wpy[i * 256 + jj], ap);
    ap = fmaf(y_prev, Wpy[128 * 256 + jj], ap);
    float cp = fmaxf(ap, 0.f) * ppr[jj];

    float aqv = Aq[(size_t)t * 256 + jj];
#pragma unroll 4
    for (int i = 0; i < 128; ++i) aqv = fmaf(hp[i], Wqy[(128 + i) * 256 + jj], aqv);
    float cq = fmaxf(aqv, 0.f) * qpr[jj];

    float az = 0.f;
#pragma unroll 4
    for (int m = 0; m < 64; ++m) az = fmaf(zp[m], Wpz[m * 256 + jj], az);
    pzh[jj] = fmaxf(az, 0.f);

    float ad = 0.f;
#pragma unroll 4
    for (int i = 0; i < 128; ++i) ad = fmaf(xdv[i], Wd[i * 256 + jj], ad);
#pragma unroll 4
    for (int m = 0; m < 64; ++m) ad = fmaf(ztv[m], Wd[(128 + m) * 256 + jj], ad);
    ad = fmaf(y_t, Wd[192 * 256 + jj], ad);
    dhv[jj] = fmaxf(ad, 0.f);
    __syncthreads();

    {
        const int i_ = tid & 127;
        const float* W = (tid < 128) ? Wdm : Wds;
        float a = 0.f;
#pragma unroll 4
        for (int q2 = 0; q2 < 256; ++q2) a = fmaf(dhv[q2], W[q2 * 128 + i_], a);
        if (tid < 128) dmv[i_] = a; else dsv[i_] = softplusf_(a);
    }
    if (tid < 128) {
        const int m = tid & 63;
        const float* W = (tid < 64) ? Wpzm : Wpzs;
        float a = 0.f;
#pragma unroll 4
        for (int q2 = 0; q2 < 256; ++q2) a = fmaf(pzh[q2], W[q2 * 64 + m], a);
        if (tid < 64) pmv[m] = a; else psv[m] = softplusf_(a);
    }
    __syncthreads();

    float kldc = 0.f, recc = 0.f;
    if (tid < 64) {
        float es = esv[tid], em = emv[tid], pm = pmv[tid], ps = psv[tid];
        float d = em - pm;
        kldc = __logf(ps / es) + (es * es + d * d) / (2.f * ps * ps) - 0.5f;
    }
    if (tid < 128) {
        float dm = dmv[tid], ds = dsv[tid], xv = xcv[tid];
        float d = xv - dm;
        recc = CC + __logf(ds) + d * d / (2.f * ds * ds);
    }

#pragma unroll
    for (int d = 1; d < 64; d <<= 1) {
        cp += __shfl_xor(cp, d);
        cq += __shfl_xor(cq, d);
        kldc += __shfl_xor(kldc, d);
        recc += __shfl_xor(recc, d);
    }
    if ((tid & 63) == 0) {
        const int w = tid >> 6;
        rl[w * 4 + 0] = cp; rl[w * 4 + 1] = cq;
        rl[w * 4 + 2] = kldc; rl[w * 4 + 3] = recc;
    }
    __syncthreads();
    if (tid == 0) {
        float plog = rl[0] + rl[4] + rl[8]  + rl[12];
        float qlog = rl[1] + rl[5] + rl[9]  + rl[13];
        float kld  = rl[2] + rl[6] + rl[10] + rl[14];
        float rec  = rl[3] + rl[7] + rl[11] + rl[15];
        float p = sigmoidf_(plog), q = sigmoidf_(qlog);
        float bce  = -(y_t * __logf(p) + (1.f - y_t) * __logf(1.f - p));
        float addt = y_t * __logf(p * q) + (1.f - y_t) * __logf((1.f - p) * (1.f - q));
        float kcat = p * __logf(p / q) + (1.f - p) * __logf((1.f - p) / (1.f - q));
        float ul = 1.f - lf;
        float* pr = part + (size_t)t * 7;
        pr[0] = lf * kld;  pr[1] = lf * rec;  pr[2] = lf * bce;
        pr[3] = ul * kld;  pr[4] = ul * rec;  pr[5] = ul * kcat;
        pr[6] = lf * addt;
    }
}

__global__ __launch_bounds__(256) void k_final(const float* __restrict__ part,
                                               float* __restrict__ out)
{
    const int o = blockIdx.x;
    float s = 0.f;
    for (int b = threadIdx.x; b < T; b += 256) s += part[(size_t)b * 7 + o];
#pragma unroll
    for (int d = 1; d < 64; d <<= 1) s += __shfl_xor(s, d);
    __shared__ float l[4];
    if ((threadIdx.x & 63) == 0) l[threadIdx.x >> 6] = s;
    __syncthreads();
    if (threadIdx.x == 0) out[o] = (l[0] + l[1]) + (l[2] + l[3]);
}

extern "C" void kernel_launch(void* const* d_in, const int* in_sizes, int n_in,
                              void* d_out, int out_size, void* d_ws, size_t ws_size,
                              hipStream_t stream) {
    (void)in_sizes; (void)n_in; (void)out_size; (void)ws_size;
    const float* x    = (const float*)d_in[0];
    const float* yin  = (const float*)d_in[1];
    const float* ez   = (const float*)d_in[2];
    const float* eu   = (const float*)d_in[3];
    const float* Wpz  = (const float*)d_in[4];
    const float* Wpzm = (const float*)d_in[5];
    const float* Wpzs = (const float*)d_in[6];
    const float* Wpy  = (const float*)d_in[7];
    const float* ppr  = (const float*)d_in[8];
    const float* Wqy  = (const float*)d_in[9];
    const float* qpr  = (const float*)d_in[10];
    const float* Wenc = (const float*)d_in[11];
    const float* Wem  = (const float*)d_in[12];
    const float* Wes  = (const float*)d_in[13];
    const float* Wd   = (const float*)d_in[14];
    const float* Wdm  = (const float*)d_in[15];
    const float* Wds  = (const float*)d_in[16];
    const float* Wih  = (const float*)d_in[17];
    const float* Whh  = (const float*)d_in[18];

    float* ws = (float*)d_ws;
    float* Aq    = ws;                           // T*256
    float* Ae    = Aq    + (size_t)T * 256;      // T*256
    float* Ah    = Ae    + (size_t)T * 256;      // T*128
    float* h_st  = Ah    + (size_t)T * 128;      // T*128
    float* z_st  = h_st  + (size_t)T * 128;      // T*64
    float* em_st = z_st  + (size_t)T * 64;       // T*64
    float* es_st = em_st + (size_t)T * 64;       // T*64
    float* y_st  = es_st + (size_t)T * 64;       // T
    float* part  = y_st  + (size_t)T;            // T*7
    float* leu   = part  + (size_t)T * 7;        // T

    k_pre<<<T / 16, 256, 0, stream>>>(x, eu, Wqy, Wenc, Wih, Aq, Ae, Ah, leu);
    k_scan<<<1, 256, 0, stream>>>(Wqy, qpr, Wenc, Wem, Wes, Wih, Whh,
                                  yin, leu, ez, Aq, Ae, Ah,
                                  h_st, z_st, em_st, es_st, y_st);
    k_post<<<T, 256, 0, stream>>>(x, yin, Wpz, Wpzm, Wpzs, Wpy, ppr, Wqy, qpr,
                                  Wd, Wdm, Wds, Aq, h_st, z_st, em_st, es_st,
                                  y_st, part);
    k_final<<<7, 256, 0, stream>>>(part, (float*)d_out);
}